// Round 5
// baseline (2843.743 us; speedup 1.0000x reference)
//
#include <hip/hip_runtime.h>

#define BATCH 2097152
#define EPS 1e-5f

// Inline tanh: no libm call (tanhf -> __ocml_tanh_f32 ABI forces spills).
// tanh(x) = 1 - 2/(exp(2x)+1); __expf = v_exp_f32, __fdividef = v_rcp_f32.
__device__ __forceinline__ float fast_tanh(float x) {
    float cx = fminf(fmaxf(x, -15.0f), 15.0f);   // avoid inf/inf
    float e  = __expf(2.0f * cx);
    return fmaf(-2.0f, __fdividef(1.0f, e + 1.0f), 1.0f);
}

// amdgpu_waves_per_eu(2,2): pin the register allocator's occupancy target to
// 2 waves/EU (8/CU) -> 256-VGPR budget. Round 4 evidence: with only a MIN
// bound (launch_bounds 2nd arg) the allocator chased max occupancy, chose
// VGPR=64, and spilled ~790 B/thread to scratch (WRITE_SIZE 2.18 GB vs
// 0.54 GB of real output). Peak live state here is ~100 floats.
__global__ __launch_bounds__(256)
__attribute__((amdgpu_waves_per_eu(2, 2)))
void spectral_kernel(
    const float* __restrict__ x,
    const float* __restrict__ w_rgb1, const float* __restrict__ b_rgb1,
    const float* __restrict__ w_rgb2, const float* __restrict__ b_rgb2,
    const float* __restrict__ w_ir1,  const float* __restrict__ b_ir1,
    const float* __restrict__ w_ir2,  const float* __restrict__ b_ir2,
    const float* __restrict__ w_n1,   const float* __restrict__ b_n1,
    const float* __restrict__ w_n2,   const float* __restrict__ b_n2,
    const float* __restrict__ w_comb, const float* __restrict__ b_comb,
    const float* __restrict__ ln_g,   const float* __restrict__ ln_b,
    const float* __restrict__ w_s1,   const float* __restrict__ b_s1,
    const float* __restrict__ w_s2,   const float* __restrict__ b_s2,
    float* __restrict__ out)
{
    const int row = blockIdx.x * blockDim.x + threadIdx.x;
    if (row >= BATCH) return;

    const float4* xv = reinterpret_cast<const float4*>(x);
    const float4 x0 = xv[(size_t)row * 2 + 0];
    const float4 x1 = xv[(size_t)row * 2 + 1];
    const float in0 = x0.x, in1 = x0.y, in2 = x0.z;   // rgb: cols 0,1,2
    const float in3 = x0.w, in4 = x1.x;               // ir/uv: cols 3,4
    const float in5 = x1.y, in6 = x1.z, in7 = x1.w;   // normals: cols 5,6,7

    float comb[32];

    // ---- rgb branch: 3 -> 16 (relu) -> 16 ----
    {
        float hb[16];
        #pragma unroll
        for (int j = 0; j < 16; ++j) {
            float s = b_rgb1[j];
            s = fmaf(w_rgb1[j * 3 + 0], in0, s);
            s = fmaf(w_rgb1[j * 3 + 1], in1, s);
            s = fmaf(w_rgb1[j * 3 + 2], in2, s);
            hb[j] = fmaxf(s, 0.0f);
        }
        #pragma unroll
        for (int j = 0; j < 16; ++j) {
            float s = b_rgb2[j];
            #pragma unroll
            for (int c = 0; c < 16; ++c)
                s = fmaf(w_rgb2[j * 16 + c], hb[c], s);
            comb[j] = s;
        }
    }

    // ---- ir branch: 2 -> 8 (relu) -> 8 ----
    {
        float hb[8];
        #pragma unroll
        for (int j = 0; j < 8; ++j) {
            float s = b_ir1[j];
            s = fmaf(w_ir1[j * 2 + 0], in3, s);
            s = fmaf(w_ir1[j * 2 + 1], in4, s);
            hb[j] = fmaxf(s, 0.0f);
        }
        #pragma unroll
        for (int j = 0; j < 8; ++j) {
            float s = b_ir2[j];
            #pragma unroll
            for (int c = 0; c < 8; ++c)
                s = fmaf(w_ir2[j * 8 + c], hb[c], s);
            comb[16 + j] = s;
        }
    }

    // ---- normals branch: 3 -> 8 (relu) -> 8 ----
    {
        float hb[8];
        #pragma unroll
        for (int j = 0; j < 8; ++j) {
            float s = b_n1[j];
            s = fmaf(w_n1[j * 3 + 0], in5, s);
            s = fmaf(w_n1[j * 3 + 1], in6, s);
            s = fmaf(w_n1[j * 3 + 2], in7, s);
            hb[j] = fmaxf(s, 0.0f);
        }
        #pragma unroll
        for (int j = 0; j < 8; ++j) {
            float s = b_n2[j];
            #pragma unroll
            for (int c = 0; c < 8; ++c)
                s = fmaf(w_n2[j * 8 + c], hb[c], s);
            comb[24 + j] = s;
        }
    }

    // ---- combine: 32 -> 64 ----
    float h[64];
    #pragma unroll
    for (int j = 0; j < 64; ++j) {
        float s = b_comb[j];
        #pragma unroll
        for (int k = 0; k < 32; ++k)
            s = fmaf(w_comb[j * 32 + k], comb[k], s);
        h[j] = s;
    }

    // ---- layernorm + tanh (base overwrites h in place) ----
    float mu = 0.0f;
    #pragma unroll
    for (int j = 0; j < 64; ++j) mu += h[j];
    mu *= (1.0f / 64.0f);
    float var = 0.0f;
    #pragma unroll
    for (int j = 0; j < 64; ++j) {
        float d = h[j] - mu;
        var = fmaf(d, d, var);
    }
    var *= (1.0f / 64.0f);
    const float inv = rsqrtf(var + EPS);

    #pragma unroll
    for (int j = 0; j < 64; ++j) {
        float t = (h[j] - mu) * inv;
        h[j] = fast_tanh(fmaf(t, ln_g[j], ln_b[j]));   // h[] now holds base
    }

    // ---- enhance layer 1: 64 -> 32 (relu) ----
    float hid[32];
    #pragma unroll
    for (int j = 0; j < 32; ++j) {
        float s = b_s1[j];
        #pragma unroll
        for (int k = 0; k < 64; ++k)
            s = fmaf(w_s1[j * 64 + k], h[k], s);
        hid[j] = fmaxf(s, 0.0f);
    }

    // ---- enhance layer 2: 32 -> 64, fused with residual add + store ----
    float4* ov = reinterpret_cast<float4*>(out) + (size_t)row * 16;
    #pragma unroll
    for (int g = 0; g < 16; ++g) {
        float r[4];
        #pragma unroll
        for (int q = 0; q < 4; ++q) {
            const int j = g * 4 + q;
            float s = b_s2[j];
            #pragma unroll
            for (int k = 0; k < 32; ++k)
                s = fmaf(w_s2[j * 32 + k], hid[k], s);
            r[q] = h[j] + s;
        }
        ov[g] = make_float4(r[0], r[1], r[2], r[3]);
    }
}

extern "C" void kernel_launch(void* const* d_in, const int* in_sizes, int n_in,
                              void* d_out, int out_size, void* d_ws, size_t ws_size,
                              hipStream_t stream) {
    const float* x      = (const float*)d_in[0];
    const float* w_rgb1 = (const float*)d_in[1];
    const float* b_rgb1 = (const float*)d_in[2];
    const float* w_rgb2 = (const float*)d_in[3];
    const float* b_rgb2 = (const float*)d_in[4];
    const float* w_ir1  = (const float*)d_in[5];
    const float* b_ir1  = (const float*)d_in[6];
    const float* w_ir2  = (const float*)d_in[7];
    const float* b_ir2  = (const float*)d_in[8];
    const float* w_n1   = (const float*)d_in[9];
    const float* b_n1   = (const float*)d_in[10];
    const float* w_n2   = (const float*)d_in[11];
    const float* b_n2   = (const float*)d_in[12];
    const float* w_comb = (const float*)d_in[13];
    const float* b_comb = (const float*)d_in[14];
    const float* ln_g   = (const float*)d_in[15];
    const float* ln_b   = (const float*)d_in[16];
    const float* w_s1   = (const float*)d_in[17];
    const float* b_s1   = (const float*)d_in[18];
    const float* w_s2   = (const float*)d_in[19];
    const float* b_s2   = (const float*)d_in[20];
    float* out = (float*)d_out;

    const int threads = 256;
    const int blocks = (BATCH + threads - 1) / threads;
    spectral_kernel<<<blocks, threads, 0, stream>>>(
        x, w_rgb1, b_rgb1, w_rgb2, b_rgb2, w_ir1, b_ir1, w_ir2, b_ir2,
        w_n1, b_n1, w_n2, b_n2, w_comb, b_comb, ln_g, ln_b,
        w_s1, b_s1, w_s2, b_s2, out);
}

// Round 6
// 1536.602 us; speedup vs baseline: 1.8507x; 1.8507x over previous
//
#include <hip/hip_runtime.h>

#define BATCH 2097152
#define EPS 1e-5f

// Per-thread state lives in ext_vector SSA values, NOT arrays. Rounds 3-5
// proved the arrays were never promoted out of scratch (VGPR stayed 64-88
// with ~1.7 GB of scratch write traffic even when the allocator was allowed
// 256 VGPRs). Vector values are first-class registers; dynamic indexing
// would lower to v_movrel, never to scratch buffer ops.
typedef float f32x8  __attribute__((ext_vector_type(8)));
typedef float f32x16 __attribute__((ext_vector_type(16)));

// Inline tanh: no libm call (tanhf -> __ocml_tanh_f32 ABI forced spills).
__device__ __forceinline__ float fast_tanh(float x) {
    float cx = fminf(fmaxf(x, -15.0f), 15.0f);   // avoid inf/inf
    float e  = __expf(2.0f * cx);
    return fmaf(-2.0f, __fdividef(1.0f, e + 1.0f), 1.0f);
}

__global__ __launch_bounds__(256) void spectral_kernel(
    const float* __restrict__ x,
    const float* __restrict__ w_rgb1, const float* __restrict__ b_rgb1,
    const float* __restrict__ w_rgb2, const float* __restrict__ b_rgb2,
    const float* __restrict__ w_ir1,  const float* __restrict__ b_ir1,
    const float* __restrict__ w_ir2,  const float* __restrict__ b_ir2,
    const float* __restrict__ w_n1,   const float* __restrict__ b_n1,
    const float* __restrict__ w_n2,   const float* __restrict__ b_n2,
    const float* __restrict__ w_comb, const float* __restrict__ b_comb,
    const float* __restrict__ ln_g,   const float* __restrict__ ln_b,
    const float* __restrict__ w_s1,   const float* __restrict__ b_s1,
    const float* __restrict__ w_s2,   const float* __restrict__ b_s2,
    float* __restrict__ out)
{
    const int row = blockIdx.x * blockDim.x + threadIdx.x;
    if (row >= BATCH) return;

    const float4* xv = reinterpret_cast<const float4*>(x);
    const float4 x0 = xv[(size_t)row * 2 + 0];
    const float4 x1 = xv[(size_t)row * 2 + 1];
    const float in0 = x0.x, in1 = x0.y, in2 = x0.z;   // rgb: cols 0,1,2
    const float in3 = x0.w, in4 = x1.x;               // ir/uv: cols 3,4
    const float in5 = x1.y, in6 = x1.z, in7 = x1.w;   // normals: cols 5,6,7

    // ---- rgb branch: 3 -> 16 (relu) -> 16  => comb0 ----
    f32x16 rh;
    #pragma unroll
    for (int j = 0; j < 16; ++j) {
        float s = b_rgb1[j];
        s = fmaf(w_rgb1[j * 3 + 0], in0, s);
        s = fmaf(w_rgb1[j * 3 + 1], in1, s);
        s = fmaf(w_rgb1[j * 3 + 2], in2, s);
        rh[j] = fmaxf(s, 0.0f);
    }
    f32x16 comb0;
    #pragma unroll
    for (int j = 0; j < 16; ++j) {
        float s = b_rgb2[j];
        #pragma unroll
        for (int c = 0; c < 16; ++c)
            s = fmaf(w_rgb2[j * 16 + c], rh[c], s);
        comb0[j] = s;
    }

    // ---- ir branch: 2 -> 8 (relu) -> 8  => comb1[0..7] ----
    f32x16 comb1;
    {
        f32x8 ih;
        #pragma unroll
        for (int j = 0; j < 8; ++j) {
            float s = b_ir1[j];
            s = fmaf(w_ir1[j * 2 + 0], in3, s);
            s = fmaf(w_ir1[j * 2 + 1], in4, s);
            ih[j] = fmaxf(s, 0.0f);
        }
        #pragma unroll
        for (int j = 0; j < 8; ++j) {
            float s = b_ir2[j];
            #pragma unroll
            for (int c = 0; c < 8; ++c)
                s = fmaf(w_ir2[j * 8 + c], ih[c], s);
            comb1[j] = s;
        }
    }

    // ---- normals branch: 3 -> 8 (relu) -> 8  => comb1[8..15] ----
    {
        f32x8 nh;
        #pragma unroll
        for (int j = 0; j < 8; ++j) {
            float s = b_n1[j];
            s = fmaf(w_n1[j * 3 + 0], in5, s);
            s = fmaf(w_n1[j * 3 + 1], in6, s);
            s = fmaf(w_n1[j * 3 + 2], in7, s);
            nh[j] = fmaxf(s, 0.0f);
        }
        #pragma unroll
        for (int j = 0; j < 8; ++j) {
            float s = b_n2[j];
            #pragma unroll
            for (int c = 0; c < 8; ++c)
                s = fmaf(w_n2[j * 8 + c], nh[c], s);
            comb1[8 + j] = s;
        }
    }

    // ---- combine: 32 -> 64, h in four f32x16 chunks ----
    f32x16 h0, h1, h2, h3;
#define COMBINE_CHUNK(HV, C0)                                         \
    {                                                                 \
        _Pragma("unroll")                                             \
        for (int j = 0; j < 16; ++j) {                                \
            const int jg = (C0) + j;                                  \
            float s = b_comb[jg];                                     \
            _Pragma("unroll")                                         \
            for (int k = 0; k < 16; ++k)                              \
                s = fmaf(w_comb[jg * 32 + k],      comb0[k], s);      \
            _Pragma("unroll")                                         \
            for (int k = 0; k < 16; ++k)                              \
                s = fmaf(w_comb[jg * 32 + 16 + k], comb1[k], s);      \
            HV[j] = s;                                                \
        }                                                             \
    }
    COMBINE_CHUNK(h0, 0)
    COMBINE_CHUNK(h1, 16)
    COMBINE_CHUNK(h2, 32)
    COMBINE_CHUNK(h3, 48)
#undef COMBINE_CHUNK

    // ---- layernorm stats ----
    float mu = 0.0f;
    #pragma unroll
    for (int k = 0; k < 16; ++k)
        mu += (h0[k] + h1[k]) + (h2[k] + h3[k]);
    mu *= (1.0f / 64.0f);

    float var = 0.0f;
    #pragma unroll
    for (int k = 0; k < 16; ++k) {
        float d0 = h0[k] - mu, d1 = h1[k] - mu;
        float d2 = h2[k] - mu, d3 = h3[k] - mu;
        var = fmaf(d0, d0, var);
        var = fmaf(d1, d1, var);
        var = fmaf(d2, d2, var);
        var = fmaf(d3, d3, var);
    }
    var *= (1.0f / 64.0f);
    const float inv = rsqrtf(var + EPS);

    // ---- normalize + affine + tanh (h chunks now hold base) ----
#define LN_TANH_CHUNK(HV, C0)                                         \
    {                                                                 \
        _Pragma("unroll")                                             \
        for (int j = 0; j < 16; ++j) {                                \
            float t = (HV[j] - mu) * inv;                             \
            HV[j] = fast_tanh(fmaf(t, ln_g[(C0) + j], ln_b[(C0) + j])); \
        }                                                             \
    }
    LN_TANH_CHUNK(h0, 0)
    LN_TANH_CHUNK(h1, 16)
    LN_TANH_CHUNK(h2, 32)
    LN_TANH_CHUNK(h3, 48)
#undef LN_TANH_CHUNK

    // ---- enhance layer 1: 64 -> 32 (relu), hid in two f32x16 ----
    f32x16 hid0, hid1;
#define S1_CHUNK(OV, C0)                                              \
    {                                                                 \
        _Pragma("unroll")                                             \
        for (int j = 0; j < 16; ++j) {                                \
            const int jg = (C0) + j;                                  \
            float s = b_s1[jg];                                       \
            _Pragma("unroll")                                         \
            for (int k = 0; k < 16; ++k)                              \
                s = fmaf(w_s1[jg * 64 + k],      h0[k], s);           \
            _Pragma("unroll")                                         \
            for (int k = 0; k < 16; ++k)                              \
                s = fmaf(w_s1[jg * 64 + 16 + k], h1[k], s);           \
            _Pragma("unroll")                                         \
            for (int k = 0; k < 16; ++k)                              \
                s = fmaf(w_s1[jg * 64 + 32 + k], h2[k], s);           \
            _Pragma("unroll")                                         \
            for (int k = 0; k < 16; ++k)                              \
                s = fmaf(w_s1[jg * 64 + 48 + k], h3[k], s);           \
            OV[j] = fmaxf(s, 0.0f);                                   \
        }                                                             \
    }
    S1_CHUNK(hid0, 0)
    S1_CHUNK(hid1, 16)
#undef S1_CHUNK

    // ---- enhance layer 2: 32 -> 64, fused residual add + float4 store ----
    float4* ov = reinterpret_cast<float4*>(out) + (size_t)row * 16;
#define S2_CHUNK(BV, C0)                                              \
    {                                                                 \
        _Pragma("unroll")                                             \
        for (int g = 0; g < 4; ++g) {                                 \
            float r[4];                                               \
            _Pragma("unroll")                                         \
            for (int q = 0; q < 4; ++q) {                             \
                const int j  = g * 4 + q;                             \
                const int jg = (C0) + j;                              \
                float s = b_s2[jg];                                   \
                _Pragma("unroll")                                     \
                for (int k = 0; k < 16; ++k)                          \
                    s = fmaf(w_s2[jg * 32 + k],      hid0[k], s);     \
                _Pragma("unroll")                                     \
                for (int k = 0; k < 16; ++k)                          \
                    s = fmaf(w_s2[jg * 32 + 16 + k], hid1[k], s);     \
                r[q] = BV[j] + s;                                     \
            }                                                         \
            ov[(C0) / 4 + g] = make_float4(r[0], r[1], r[2], r[3]);   \
        }                                                             \
    }
    S2_CHUNK(h0, 0)
    S2_CHUNK(h1, 16)
    S2_CHUNK(h2, 32)
    S2_CHUNK(h3, 48)
#undef S2_CHUNK
}

extern "C" void kernel_launch(void* const* d_in, const int* in_sizes, int n_in,
                              void* d_out, int out_size, void* d_ws, size_t ws_size,
                              hipStream_t stream) {
    const float* x      = (const float*)d_in[0];
    const float* w_rgb1 = (const float*)d_in[1];
    const float* b_rgb1 = (const float*)d_in[2];
    const float* w_rgb2 = (const float*)d_in[3];
    const float* b_rgb2 = (const float*)d_in[4];
    const float* w_ir1  = (const float*)d_in[5];
    const float* b_ir1  = (const float*)d_in[6];
    const float* w_ir2  = (const float*)d_in[7];
    const float* b_ir2  = (const float*)d_in[8];
    const float* w_n1   = (const float*)d_in[9];
    const float* b_n1   = (const float*)d_in[10];
    const float* w_n2   = (const float*)d_in[11];
    const float* b_n2   = (const float*)d_in[12];
    const float* w_comb = (const float*)d_in[13];
    const float* b_comb = (const float*)d_in[14];
    const float* ln_g   = (const float*)d_in[15];
    const float* ln_b   = (const float*)d_in[16];
    const float* w_s1   = (const float*)d_in[17];
    const float* b_s1   = (const float*)d_in[18];
    const float* w_s2   = (const float*)d_in[19];
    const float* b_s2   = (const float*)d_in[20];
    float* out = (float*)d_out;

    const int threads = 256;
    const int blocks = (BATCH + threads - 1) / threads;
    spectral_kernel<<<blocks, threads, 0, stream>>>(
        x, w_rgb1, b_rgb1, w_rgb2, b_rgb2, w_ir1, b_ir1, w_ir2, b_ir2,
        w_n1, b_n1, w_n2, b_n2, w_comb, b_comb, ln_g, ln_b,
        w_s1, b_s1, w_s2, b_s2, out);
}